// Round 17
// baseline (185.831 us; speedup 1.0000x reference)
//
#include <hip/hip_runtime.h>

#define HH   112
#define WW   320
#define CIN_ 128
#define HW_  (HH * WW)        // 35840
#define CHUNK 32              // max pixels per queue item (2 rounds of 16)

__device__ __forceinline__ float lrelu(float v) {
    return v >= 0.f ? v : 0.01f * v;
}

// ============================================================================
// K1: stage 1 (per-line grouped 1x1 chain) -> inds1 + xT dump; zeroes qcounts.
// 2 blocks per line (512 thr), 5 tiles of 32 px, 4 chains per wave.
// [round-12 proven, 181us, bit-exact]
// ============================================================================
__global__ __launch_bounds__(512, 2)
void k1_stage1(const float* __restrict__ x_in,
               const float* __restrict__ w1_0, const float* __restrict__ b1_0,
               const float* __restrict__ w1_1, const float* __restrict__ b1_1,
               const float* __restrict__ w1_2, const float* __restrict__ b1_2,
               int* __restrict__ inds1_out, float* __restrict__ xT_out,
               int* __restrict__ qc2, int* __restrict__ qc3)
{
    __shared__ float w1s0[32][CIN_ + 1];
    __shared__ float w1s1[32][33];
    __shared__ float w1s2[16][33];
    __shared__ float b1s[80];
    __shared__ float xT[32][132];          // 32-px tile, float4-aligned rows
    __shared__ float ys[8][4][32];         // [wave][chain][32], wave-private

    const int h   = blockIdx.x >> 1;
    const int q   = blockIdx.x & 1;
    const int tid = threadIdx.x;
    const int base = h * WW;

    if (blockIdx.x == 0 && tid == 0) { *qc2 = 0; *qc3 = 0; }

    for (int n = tid; n < 32 * CIN_; n += 512)
        w1s0[n >> 7][n & 127] = w1_0[h * (32 * CIN_) + n];
    for (int n = tid; n < 32 * 32; n += 512)
        w1s1[n >> 5][n & 31] = w1_1[h * 1024 + n];
    if (tid < 16 * 32)
        w1s2[tid >> 5][tid & 31] = w1_2[h * 512 + tid];
    if      (tid < 32) b1s[tid] = b1_0[h * 32 + tid];
    else if (tid < 64) b1s[tid] = b1_1[h * 32 + (tid - 32)];
    else if (tid < 80) b1s[tid] = b1_2[h * 16 + (tid - 64)];
    __syncthreads();

    const int wave = tid >> 6;
    const int lane = tid & 63;
    const int o    = lane & 31;
    const int half = lane >> 5;
    const int o16  = lane & 15;

    for (int t = 0; t < 5; ++t) {
        const int w0 = q * 160 + t * 32;
        for (int n = tid; n < 32 * CIN_; n += 512) {
            int ww = n & 31, c = n >> 5;
            xT[ww][c] = x_in[c * HW_ + base + w0 + ww];
        }
        __syncthreads();
        for (int n = tid; n < 32 * CIN_; n += 512) {
            int pix = n >> 7, c = n & 127;
            xT_out[(size_t)(base + w0 + pix) * CIN_ + c] = xT[pix][c];
        }

        float a0 = 0.f, a1 = 0.f, a2 = 0.f, a3 = 0.f;
        #pragma unroll
        for (int i = 0; i < 64; i += 4) {
            const int ii = half * 64 + i;
            const float w0v = w1s0[o][ii];
            const float w1v = w1s0[o][ii + 1];
            const float w2v = w1s0[o][ii + 2];
            const float w3v = w1s0[o][ii + 3];
            const float4 v0 = *reinterpret_cast<const float4*>(&xT[wave * 4 + 0][ii]);
            const float4 v1 = *reinterpret_cast<const float4*>(&xT[wave * 4 + 1][ii]);
            const float4 v2 = *reinterpret_cast<const float4*>(&xT[wave * 4 + 2][ii]);
            const float4 v3 = *reinterpret_cast<const float4*>(&xT[wave * 4 + 3][ii]);
            a0 += v0.x * w0v; a1 += v1.x * w0v; a2 += v2.x * w0v; a3 += v3.x * w0v;
            a0 += v0.y * w1v; a1 += v1.y * w1v; a2 += v2.y * w1v; a3 += v3.y * w1v;
            a0 += v0.z * w2v; a1 += v1.z * w2v; a2 += v2.z * w2v; a3 += v3.z * w2v;
            a0 += v0.w * w3v; a1 += v1.w * w3v; a2 += v2.w * w3v; a3 += v3.w * w3v;
        }
        a0 += __shfl_xor(a0, 32); a1 += __shfl_xor(a1, 32);
        a2 += __shfl_xor(a2, 32); a3 += __shfl_xor(a3, 32);
        ys[wave][0][o] = lrelu(a0 + b1s[o]);
        ys[wave][1][o] = lrelu(a1 + b1s[o]);
        ys[wave][2][o] = lrelu(a2 + b1s[o]);
        ys[wave][3][o] = lrelu(a3 + b1s[o]);

        a0 = a1 = a2 = a3 = 0.f;
        #pragma unroll
        for (int i = 0; i < 32; i += 4) {
            const float w0v = w1s1[o][i];
            const float w1v = w1s1[o][i + 1];
            const float w2v = w1s1[o][i + 2];
            const float w3v = w1s1[o][i + 3];
            const float4 y0 = *reinterpret_cast<const float4*>(&ys[wave][0][i]);
            const float4 y1 = *reinterpret_cast<const float4*>(&ys[wave][1][i]);
            const float4 y2 = *reinterpret_cast<const float4*>(&ys[wave][2][i]);
            const float4 y3 = *reinterpret_cast<const float4*>(&ys[wave][3][i]);
            a0 += y0.x * w0v; a1 += y1.x * w0v; a2 += y2.x * w0v; a3 += y3.x * w0v;
            a0 += y0.y * w1v; a1 += y1.y * w1v; a2 += y2.y * w1v; a3 += y3.y * w1v;
            a0 += y0.z * w2v; a1 += y1.z * w2v; a2 += y2.z * w2v; a3 += y3.z * w2v;
            a0 += y0.w * w3v; a1 += y1.w * w3v; a2 += y2.w * w3v; a3 += y3.w * w3v;
        }
        ys[wave][0][o] = lrelu(a0 + b1s[32 + o]);
        ys[wave][1][o] = lrelu(a1 + b1s[32 + o]);
        ys[wave][2][o] = lrelu(a2 + b1s[32 + o]);
        ys[wave][3][o] = lrelu(a3 + b1s[32 + o]);

        a0 = a1 = a2 = a3 = 0.f;
        #pragma unroll
        for (int i = 0; i < 32; i += 4) {
            const float w0v = w1s2[o16][i];
            const float w1v = w1s2[o16][i + 1];
            const float w2v = w1s2[o16][i + 2];
            const float w3v = w1s2[o16][i + 3];
            const float4 y0 = *reinterpret_cast<const float4*>(&ys[wave][0][i]);
            const float4 y1 = *reinterpret_cast<const float4*>(&ys[wave][1][i]);
            const float4 y2 = *reinterpret_cast<const float4*>(&ys[wave][2][i]);
            const float4 y3 = *reinterpret_cast<const float4*>(&ys[wave][3][i]);
            a0 += y0.x * w0v; a1 += y1.x * w0v; a2 += y2.x * w0v; a3 += y3.x * w0v;
            a0 += y0.y * w1v; a1 += y1.y * w1v; a2 += y2.y * w1v; a3 += y3.y * w1v;
            a0 += y0.z * w2v; a1 += y1.z * w2v; a2 += y2.z * w2v; a3 += y3.z * w2v;
            a0 += y0.w * w3v; a1 += y1.w * w3v; a2 += y2.w * w3v; a3 += y3.w * w3v;
        }
        float bv0 = a0 + b1s[64 + o16], bv1 = a1 + b1s[64 + o16];
        float bv2 = a2 + b1s[64 + o16], bv3 = a3 + b1s[64 + o16];
        int bi0 = o16, bi1 = o16, bi2 = o16, bi3 = o16;
        #pragma unroll
        for (int d = 1; d < 16; d <<= 1) {
            const float ov0 = __shfl_xor(bv0, d); const int oi0 = __shfl_xor(bi0, d);
            const float ov1 = __shfl_xor(bv1, d); const int oi1 = __shfl_xor(bi1, d);
            const float ov2 = __shfl_xor(bv2, d); const int oi2 = __shfl_xor(bi2, d);
            const float ov3 = __shfl_xor(bv3, d); const int oi3 = __shfl_xor(bi3, d);
            if (ov0 > bv0 || (ov0 == bv0 && oi0 < bi0)) { bv0 = ov0; bi0 = oi0; }
            if (ov1 > bv1 || (ov1 == bv1 && oi1 < bi1)) { bv1 = ov1; bi1 = oi1; }
            if (ov2 > bv2 || (ov2 == bv2 && oi2 < bi2)) { bv2 = ov2; bi2 = oi2; }
            if (ov3 > bv3 || (ov3 == bv3 && oi3 < bi3)) { bv3 = ov3; bi3 = oi3; }
        }
        if (lane == 0) {
            inds1_out[base + w0 + wave * 4 + 0] = bi0;
            inds1_out[base + w0 + wave * 4 + 1] = bi1;
            inds1_out[base + w0 + wave * 4 + 2] = bi2;
            inds1_out[base + w0 + wave * 4 + 3] = bi3;
        }
        __syncthreads();
    }
}

// ============================================================================
// Sorter: one block per line; bucket-sort by (clipped) routing index; emit
// <=CHUNK-pixel work items. (round-9/12 proven)
// ============================================================================
template <int BINS>
__global__ void sorter(const int* __restrict__ inds_in, int clipmax,
                       int* __restrict__ sorted, int4* __restrict__ queue,
                       int* __restrict__ qcount)
{
    __shared__ int cnt[BINS];
    __shared__ int scan[BINS];
    __shared__ int rank[BINS];

    const int h = blockIdx.x, tid = threadIdx.x, base = h * WW;
    if (tid < BINS) { cnt[tid] = 0; rank[tid] = 0; }
    __syncthreads();

    int c = -1;
    if (tid < WW) {
        c = inds_in[base + tid];
        c = min(max(c, 0), clipmax);
        atomicAdd(&cnt[c], 1);
    }
    __syncthreads();
    if (tid < BINS) scan[tid] = cnt[tid];
    __syncthreads();
    for (int s = 1; s < BINS; s <<= 1) {
        int v = 0;
        if (tid >= s && tid < BINS) v = scan[tid - s];
        __syncthreads();
        if (tid < BINS) scan[tid] += v;
        __syncthreads();
    }
    if (tid < WW) {
        int pos = (scan[c] - cnt[c]) + atomicAdd(&rank[c], 1);
        sorted[base + pos] = base + tid;          // absolute pixel id
    }
    if (tid < BINS && cnt[tid] > 0) {
        int offc = scan[tid] - cnt[tid];
        for (int s0 = 0; s0 < cnt[tid]; s0 += CHUNK) {
            int qi = atomicAdd(qcount, 1);
            queue[qi] = make_int4(h, tid, base + offc + s0,
                                  min(CHUNK, cnt[tid] - s0));
        }
    }
}

// ============================================================================
// QK round macro — byte-identical arithmetic to the proven round-9/12 kernel.
// ============================================================================
#define QK_ROUND(TB, PA, PB, PC, PD)                                           \
{                                                                              \
    float a0 = 0.f, a1 = 0.f, a2 = 0.f, a3 = 0.f;                              \
    _Pragma("unroll")                                                          \
    for (int i = 0; i < 64; i += 4) {                                          \
        const int ii = half * 64 + i;                                          \
        const float w0v = ws0[(ii + 0) * 32 + o];                              \
        const float w1v = ws0[(ii + 1) * 32 + o];                              \
        const float w2v = ws0[(ii + 2) * 32 + o];                              \
        const float w3v = ws0[(ii + 3) * 32 + o];                              \
        const float4 v0 = *reinterpret_cast<const float4*>(&xbuf[wave*4+0][ii]);\
        const float4 v1 = *reinterpret_cast<const float4*>(&xbuf[wave*4+1][ii]);\
        const float4 v2 = *reinterpret_cast<const float4*>(&xbuf[wave*4+2][ii]);\
        const float4 v3 = *reinterpret_cast<const float4*>(&xbuf[wave*4+3][ii]);\
        a0 += v0.x * w0v; a1 += v1.x * w0v; a2 += v2.x * w0v; a3 += v3.x * w0v;\
        a0 += v0.y * w1v; a1 += v1.y * w1v; a2 += v2.y * w1v; a3 += v3.y * w1v;\
        a0 += v0.z * w2v; a1 += v1.z * w2v; a2 += v2.z * w2v; a3 += v3.z * w2v;\
        a0 += v0.w * w3v; a1 += v1.w * w3v; a2 += v2.w * w3v; a3 += v3.w * w3v;\
    }                                                                          \
    a0 += __shfl_xor(a0, 32); a1 += __shfl_xor(a1, 32);                        \
    a2 += __shfl_xor(a2, 32); a3 += __shfl_xor(a3, 32);                        \
    ys[wave][0][o] = lrelu(a0 + bs[o]);                                        \
    ys[wave][1][o] = lrelu(a1 + bs[o]);                                        \
    ys[wave][2][o] = lrelu(a2 + bs[o]);                                        \
    ys[wave][3][o] = lrelu(a3 + bs[o]);                                        \
    a0 = a1 = a2 = a3 = 0.f;                                                   \
    _Pragma("unroll")                                                          \
    for (int i = 0; i < 32; i += 4) {                                          \
        const float w0v = ws1[(i + 0) * 32 + o];                               \
        const float w1v = ws1[(i + 1) * 32 + o];                               \
        const float w2v = ws1[(i + 2) * 32 + o];                               \
        const float w3v = ws1[(i + 3) * 32 + o];                               \
        const float4 y0 = *reinterpret_cast<const float4*>(&ys[wave][0][i]);   \
        const float4 y1 = *reinterpret_cast<const float4*>(&ys[wave][1][i]);   \
        const float4 y2 = *reinterpret_cast<const float4*>(&ys[wave][2][i]);   \
        const float4 y3 = *reinterpret_cast<const float4*>(&ys[wave][3][i]);   \
        a0 += y0.x * w0v; a1 += y1.x * w0v; a2 += y2.x * w0v; a3 += y3.x * w0v;\
        a0 += y0.y * w1v; a1 += y1.y * w1v; a2 += y2.y * w1v; a3 += y3.y * w1v;\
        a0 += y0.z * w2v; a1 += y1.z * w2v; a2 += y2.z * w2v; a3 += y3.z * w2v;\
        a0 += y0.w * w3v; a1 += y1.w * w3v; a2 += y2.w * w3v; a3 += y3.w * w3v;\
    }                                                                          \
    ys[wave][0][o] = lrelu(a0 + bs[32 + o]);                                   \
    ys[wave][1][o] = lrelu(a1 + bs[32 + o]);                                   \
    ys[wave][2][o] = lrelu(a2 + bs[32 + o]);                                   \
    ys[wave][3][o] = lrelu(a3 + bs[32 + o]);                                   \
    a0 = a1 = a2 = a3 = 0.f;                                                   \
    _Pragma("unroll")                                                          \
    for (int i = 0; i < 32; i += 4) {                                          \
        const float w0v = ws2[(i + 0) * 32 + o];                               \
        const float w1v = ws2[(i + 1) * 32 + o];                               \
        const float w2v = ws2[(i + 2) * 32 + o];                               \
        const float w3v = ws2[(i + 3) * 32 + o];                               \
        const float4 y0 = *reinterpret_cast<const float4*>(&ys[wave][0][i]);   \
        const float4 y1 = *reinterpret_cast<const float4*>(&ys[wave][1][i]);   \
        const float4 y2 = *reinterpret_cast<const float4*>(&ys[wave][2][i]);   \
        const float4 y3 = *reinterpret_cast<const float4*>(&ys[wave][3][i]);   \
        a0 += y0.x * w0v; a1 += y1.x * w0v; a2 += y2.x * w0v; a3 += y3.x * w0v;\
        a0 += y0.y * w1v; a1 += y1.y * w1v; a2 += y2.y * w1v; a3 += y3.y * w1v;\
        a0 += y0.z * w2v; a1 += y1.z * w2v; a2 += y2.z * w2v; a3 += y3.z * w2v;\
        a0 += y0.w * w3v; a1 += y1.w * w3v; a2 += y2.w * w3v; a3 += y3.w * w3v;\
    }                                                                          \
    float bv0 = a0 + bs[64 + o], bv1 = a1 + bs[64 + o];                        \
    float bv2 = a2 + bs[64 + o], bv3 = a3 + bs[64 + o];                        \
    int bi0 = o, bi1 = o, bi2 = o, bi3 = o;                                    \
    _Pragma("unroll")                                                          \
    for (int d = 1; d < 32; d <<= 1) {                                         \
        const float ov0 = __shfl_xor(bv0, d); const int oi0 = __shfl_xor(bi0, d);\
        const float ov1 = __shfl_xor(bv1, d); const int oi1 = __shfl_xor(bi1, d);\
        const float ov2 = __shfl_xor(bv2, d); const int oi2 = __shfl_xor(bi2, d);\
        const float ov3 = __shfl_xor(bv3, d); const int oi3 = __shfl_xor(bi3, d);\
        if (ov0 > bv0 || (ov0 == bv0 && oi0 < bi0)) { bv0 = ov0; bi0 = oi0; }  \
        if (ov1 > bv1 || (ov1 == bv1 && oi1 < bi1)) { bv1 = ov1; bi1 = oi1; }  \
        if (ov2 > bv2 || (ov2 == bv2 && oi2 < bi2)) { bv2 = ov2; bi2 = oi2; }  \
        if (ov3 > bv3 || (ov3 == bv3 && oi3 < bi3)) { bv3 = ov3; bi3 = oi3; }  \
    }                                                                          \
    if (lane == 0) {                                                           \
        const int tb4 = (TB) + wave * 4;                                       \
        if (STAGE == 2) {                                                      \
            if (tb4 + 0 < n) result[PA] = c * 16 + bi0 - 8;                    \
            if (tb4 + 1 < n) result[PB] = c * 16 + bi1 - 8;                    \
            if (tb4 + 2 < n) result[PC] = c * 16 + bi2 - 8;                    \
            if (tb4 + 3 < n) result[PD] = c * 16 + bi3 - 8;                    \
        } else {                                                               \
            if (tb4 + 0 < n) result[PA] = min(max(inds12_in[PA] * 16 + bi0 - 8, 0), 4095); \
            if (tb4 + 1 < n) result[PB] = min(max(inds12_in[PB] * 16 + bi1 - 8, 0), 4095); \
            if (tb4 + 2 < n) result[PC] = min(max(inds12_in[PC] * 16 + bi2 - 8, 0), 4095); \
            if (tb4 + 3 < n) result[PD] = min(max(inds12_in[PD] * 16 + bi3 - 8, 0), 4095); \
        }                                                                      \
    }                                                                          \
}

// ============================================================================
// Queue-driven CondMul chain — round-12 structure with ASYNC weight staging:
// wsAll is one linear LDS array ([W0|W1|W2], byte-identical layout) filled by
// __builtin_amdgcn_global_load_lds width=16 (24 chunks x 64 lanes x 16B,
// 6 chunks/wave; LDS dest = wave-uniform base + lane*16 = our linear layout).
// No VGPR round-trip; all loads issue back-to-back, drained by the barrier's
// vmcnt(0). Compute and FP order bit-identical to the proven kernel.
// ============================================================================
template <int STAGE>
__global__ __launch_bounds__(256, 4)
void qk_compute(const float* __restrict__ xT_in, const int* __restrict__ sorted,
                const int4* __restrict__ queue, const int* __restrict__ qcount,
                const float* __restrict__ W0, const float* __restrict__ Bb0,
                const float* __restrict__ W1, const float* __restrict__ Bb1,
                const float* __restrict__ W2, const float* __restrict__ Bb2,
                const int* __restrict__ inds12_in, int* __restrict__ result)
{
    __shared__ float wsAll[4096 + 1024 + 1024];   // [W0|W1|W2], linear
    __shared__ float bs[96];
    __shared__ float xbuf[16][CIN_];
    __shared__ float ys[4][4][32];

    float* const ws0 = &wsAll[0];
    float* const ws1 = &wsAll[4096];
    float* const ws2 = &wsAll[5120];

    const int tid  = threadIdx.x;
    const int wave = tid >> 6;
    const int lane = tid & 63;
    const int o    = lane & 31;
    const int half = lane >> 5;

    const int qn = *qcount;
    for (int qi = blockIdx.x; qi < qn; qi += gridDim.x) {
        const int4 it4   = queue[qi];
        const int  c     = it4.y;
        const int  start = it4.z;
        const int  n     = it4.w;
        const int  key   = (STAGE == 2) ? (it4.x * 16 + c) : (it4.x * 256 + c);
        const int  nr    = (n + 15) >> 4;
        const int  t0    = wave * 4;

        __syncthreads();                  // all waves done with previous item's LDS

        // ---- ASYNC weight staging: issue first (longest latency) ----
        const float* W0g = W0 + (size_t)key * 4096;
        const float* W1g = W1 + (size_t)key * 1024;
        const float* W2g = W2 + (size_t)key * 1024;
        #pragma unroll
        for (int k = 0; k < 6; ++k) {
            const int j = wave * 6 + k;              // chunk id, wave-uniform
            const float* src =
                (j < 16) ? (W0g + j * 256)
              : (j < 20) ? (W1g + (j - 16) * 256)
                         : (W2g + (j - 20) * 256);
            __builtin_amdgcn_global_load_lds(
                (const __attribute__((address_space(1))) unsigned int*)(src + lane * 4),
                (__attribute__((address_space(3))) unsigned int*)(wsAll + j * 256),
                16, 0, 0);
        }

        // ---- prefetch round-0 x (named scalars; 1 float2/pixel/lane) ----
        const int pA0 = sorted[start + min(t0 + 0, n - 1)];
        const int pB0 = sorted[start + min(t0 + 1, n - 1)];
        const int pC0 = sorted[start + min(t0 + 2, n - 1)];
        const int pD0 = sorted[start + min(t0 + 3, n - 1)];
        const float2 xA0 = *reinterpret_cast<const float2*>(&xT_in[(size_t)pA0 * CIN_ + 2 * lane]);
        const float2 xB0 = *reinterpret_cast<const float2*>(&xT_in[(size_t)pB0 * CIN_ + 2 * lane]);
        const float2 xC0 = *reinterpret_cast<const float2*>(&xT_in[(size_t)pC0 * CIN_ + 2 * lane]);
        const float2 xD0 = *reinterpret_cast<const float2*>(&xT_in[(size_t)pD0 * CIN_ + 2 * lane]);

        // ---- biases (small, plain loads) ----
        if      (tid < 32) bs[tid] = Bb0[(size_t)key * 32 + tid];
        else if (tid < 64) bs[tid] = Bb1[(size_t)key * 32 + (tid - 32)];
        else if (tid < 96) bs[tid] = Bb2[(size_t)key * 32 + (tid - 64)];
        __syncthreads();                  // vmcnt(0) drain covers global_load_lds

        // ---- round 0: write prefetched x, prefetch round 1 (scalars) ----
        *reinterpret_cast<float2*>(&xbuf[wave * 4 + 0][2 * lane]) = xA0;
        *reinterpret_cast<float2*>(&xbuf[wave * 4 + 1][2 * lane]) = xB0;
        *reinterpret_cast<float2*>(&xbuf[wave * 4 + 2][2 * lane]) = xC0;
        *reinterpret_cast<float2*>(&xbuf[wave * 4 + 3][2 * lane]) = xD0;

        int pA1 = 0, pB1 = 0, pC1 = 0, pD1 = 0;
        float2 xA1 = {0.f, 0.f}, xB1 = {0.f, 0.f}, xC1 = {0.f, 0.f}, xD1 = {0.f, 0.f};
        if (nr == 2) {
            pA1 = sorted[start + min(16 + t0 + 0, n - 1)];
            pB1 = sorted[start + min(16 + t0 + 1, n - 1)];
            pC1 = sorted[start + min(16 + t0 + 2, n - 1)];
            pD1 = sorted[start + min(16 + t0 + 3, n - 1)];
            xA1 = *reinterpret_cast<const float2*>(&xT_in[(size_t)pA1 * CIN_ + 2 * lane]);
            xB1 = *reinterpret_cast<const float2*>(&xT_in[(size_t)pB1 * CIN_ + 2 * lane]);
            xC1 = *reinterpret_cast<const float2*>(&xT_in[(size_t)pC1 * CIN_ + 2 * lane]);
            xD1 = *reinterpret_cast<const float2*>(&xT_in[(size_t)pD1 * CIN_ + 2 * lane]);
        }

        QK_ROUND(0, pA0, pB0, pC0, pD0)

        if (nr == 2) {
            *reinterpret_cast<float2*>(&xbuf[wave * 4 + 0][2 * lane]) = xA1;
            *reinterpret_cast<float2*>(&xbuf[wave * 4 + 1][2 * lane]) = xB1;
            *reinterpret_cast<float2*>(&xbuf[wave * 4 + 2][2 * lane]) = xC1;
            *reinterpret_cast<float2*>(&xbuf[wave * 4 + 3][2 * lane]) = xD1;
            QK_ROUND(16, pA1, pB1, pC1, pD1)
        }
    }
}

// ============================================================================
// Fallback: proven monolithic kernel (only if d_ws too small — not expected).
// ============================================================================
__global__ __launch_bounds__(512, 4)
void reg3_fused(const float* __restrict__ x_in,
                const float* __restrict__ w1_0, const float* __restrict__ b1_0,
                const float* __restrict__ w1_1, const float* __restrict__ b1_1,
                const float* __restrict__ w1_2, const float* __restrict__ b1_2,
                const float* __restrict__ w2_0, const float* __restrict__ b2_0,
                const float* __restrict__ w2_1, const float* __restrict__ b2_1,
                const float* __restrict__ w2_2, const float* __restrict__ b2_2,
                const float* __restrict__ w3_0, const float* __restrict__ b3_0,
                const float* __restrict__ w3_1, const float* __restrict__ b3_1,
                const float* __restrict__ w3_2, const float* __restrict__ b3_2,
                int* __restrict__ out)
{
    __shared__ float xT[8][CIN_ + 1];
    __shared__ float w1s0[32][CIN_ + 1];
    __shared__ float w1s1[32][33];
    __shared__ float w1s2[16][33];
    __shared__ float b1s[80];

    const int h   = blockIdx.x / 40;
    const int w0  = (blockIdx.x % 40) * 8;
    const int tid = threadIdx.x;

    for (int n = tid; n < 8 * CIN_; n += 512) {
        int ww = n & 7, c = n >> 3;
        xT[ww][c] = x_in[c * HW_ + h * WW + w0 + ww];
    }
    for (int n = tid; n < 32 * CIN_; n += 512)
        w1s0[n >> 7][n & 127] = w1_0[h * (32 * CIN_) + n];
    for (int n = tid; n < 32 * 32; n += 512)
        w1s1[n >> 5][n & 31] = w1_1[h * 1024 + n];
    if (tid < 16 * 32)
        w1s2[tid >> 5][tid & 31] = w1_2[h * 512 + tid];
    if      (tid < 32) b1s[tid] = b1_0[h * 32 + tid];
    else if (tid < 64) b1s[tid] = b1_1[h * 32 + (tid - 32)];
    else if (tid < 80) b1s[tid] = b1_2[h * 16 + (tid - 64)];
    __syncthreads();

    const int wave = tid >> 6, lane = tid & 63;
    const int o = lane & 31, half = lane >> 5, o16 = lane & 15;
    const float* xr = &xT[wave][0];

    float acc = 0.f;
    #pragma unroll
    for (int i = 0; i < 64; ++i) { int ii = half * 64 + i; acc += xr[ii] * w1s0[o][ii]; }
    acc += __shfl_xor(acc, 32);
    float y = lrelu(acc + b1s[o]);
    acc = 0.f;
    #pragma unroll
    for (int i = 0; i < 32; ++i) acc += __shfl(y, i) * w1s1[o][i];
    float y2 = lrelu(acc + b1s[32 + o]);
    acc = 0.f;
    #pragma unroll
    for (int i = 0; i < 32; ++i) acc += __shfl(y2, i) * w1s2[o16][i];
    float t1 = acc + b1s[64 + o16];

    float bv = t1; int bi = o16;
    #pragma unroll
    for (int d = 1; d < 16; d <<= 1) {
        float ov = __shfl_xor(bv, d); int oi = __shfl_xor(bi, d);
        if (ov > bv || (ov == bv && oi < bi)) { bv = ov; bi = oi; }
    }
    const int inds1 = bi;
    const int idx1  = inds1 + 16 * h;

    const float* Wp = w2_0 + (size_t)idx1 * (CIN_ * 32);
    acc = 0.f;
    #pragma unroll
    for (int i = 0; i < 64; ++i) { int ii = half * 64 + i; acc += xr[ii] * Wp[ii * 32 + o]; }
    acc += __shfl_xor(acc, 32);
    y = lrelu(acc + b2_0[idx1 * 32 + o]);
    Wp = w2_1 + (size_t)idx1 * 1024;
    acc = 0.f;
    #pragma unroll
    for (int i = 0; i < 32; ++i) acc += __shfl(y, i) * Wp[i * 32 + o];
    y2 = lrelu(acc + b2_1[idx1 * 32 + o]);
    Wp = w2_2 + (size_t)idx1 * 1024;
    acc = 0.f;
    #pragma unroll
    for (int i = 0; i < 32; ++i) acc += __shfl(y2, i) * Wp[i * 32 + o];
    float y3 = acc + b2_2[idx1 * 32 + o];

    bv = y3; bi = o;
    #pragma unroll
    for (int d = 1; d < 32; d <<= 1) {
        float ov = __shfl_xor(bv, d); int oi = __shfl_xor(bi, d);
        if (ov > bv || (ov == bv && oi < bi)) { bv = ov; bi = oi; }
    }
    const int inds2  = bi;
    const int inds12 = inds1 * 16 + inds2 - 8;
    const int clip12 = min(max(inds12, 0), 255);
    const int idx12  = clip12 + 256 * h;

    Wp = w3_0 + (size_t)idx12 * (CIN_ * 32);
    acc = 0.f;
    #pragma unroll
    for (int i = 0; i < 64; ++i) { int ii = half * 64 + i; acc += xr[ii] * Wp[ii * 32 + o]; }
    acc += __shfl_xor(acc, 32);
    y = lrelu(acc + b3_0[idx12 * 32 + o]);
    Wp = w3_1 + (size_t)idx12 * 1024;
    acc = 0.f;
    #pragma unroll
    for (int i = 0; i < 32; ++i) acc += __shfl(y, i) * Wp[i * 32 + o];
    y2 = lrelu(acc + b3_1[idx12 * 32 + o]);
    Wp = w3_2 + (size_t)idx12 * 1024;
    acc = 0.f;
    #pragma unroll
    for (int i = 0; i < 32; ++i) acc += __shfl(y2, i) * Wp[i * 32 + o];
    y3 = acc + b3_2[idx12 * 32 + o];

    bv = y3; bi = o;
    #pragma unroll
    for (int d = 1; d < 32; d <<= 1) {
        float ov = __shfl_xor(bv, d); int oi = __shfl_xor(bi, d);
        if (ov > bv || (ov == bv && oi < bi)) { bv = ov; bi = oi; }
    }
    int inds123 = inds12 * 16 + bi - 8;
    inds123 = min(max(inds123, 0), 4095);
    if (lane == 0) out[h * WW + w0 + wave] = inds123;
}

extern "C" void kernel_launch(void* const* d_in, const int* in_sizes, int n_in,
                              void* d_out, int out_size, void* d_ws, size_t ws_size,
                              hipStream_t stream)
{
    const float* x_in = (const float*)d_in[0];
    const float* w1_0 = (const float*)d_in[1];
    const float* b1_0 = (const float*)d_in[2];
    const float* w1_1 = (const float*)d_in[3];
    const float* b1_1 = (const float*)d_in[4];
    const float* w1_2 = (const float*)d_in[5];
    const float* b1_2 = (const float*)d_in[6];
    const float* w2_0 = (const float*)d_in[7];
    const float* b2_0 = (const float*)d_in[8];
    const float* w2_1 = (const float*)d_in[9];
    const float* b2_1 = (const float*)d_in[10];
    const float* w2_2 = (const float*)d_in[11];
    const float* b2_2 = (const float*)d_in[12];
    const float* w3_0 = (const float*)d_in[13];
    const float* b3_0 = (const float*)d_in[14];
    const float* w3_1 = (const float*)d_in[15];
    const float* b3_1 = (const float*)d_in[16];
    const float* w3_2 = (const float*)d_in[17];
    const float* b3_2 = (const float*)d_in[18];
    int* out = (int*)d_out;

    // ws layout (bytes)
    char* ws = (char*)d_ws;
    int*   inds1_ws  = (int*)(ws + 0);                 // HW ints
    int*   inds12_ws = (int*)(ws + 143360);            // HW ints
    int*   sorted2   = (int*)(ws + 286720);            // HW ints
    int*   sorted3   = (int*)(ws + 430080);            // HW ints
    int*   qc2       = (int*)(ws + 573440);
    int*   qc3       = (int*)(ws + 573444);
    int4*  queue2    = (int4*)(ws + 573456);           // HW entries max
    int4*  queue3    = (int4*)(ws + 1146896);          // HW entries max
    float* xT_ws     = (float*)(ws + 1720336);         // HW*128 floats
    const size_t NEED = 1720336 + (size_t)HW_ * CIN_ * 4;   // ~20.07 MB

    if (ws_size >= NEED) {
        k1_stage1<<<HH * 2, 512, 0, stream>>>(
            x_in, w1_0, b1_0, w1_1, b1_1, w1_2, b1_2,
            inds1_ws, xT_ws, qc2, qc3);
        sorter<16><<<HH, 512, 0, stream>>>(inds1_ws, 15, sorted2, queue2, qc2);
        qk_compute<2><<<2048, 256, 0, stream>>>(
            xT_ws, sorted2, queue2, qc2,
            w2_0, b2_0, w2_1, b2_1, w2_2, b2_2, nullptr, inds12_ws);
        sorter<256><<<HH, 512, 0, stream>>>(inds12_ws, 255, sorted3, queue3, qc3);
        qk_compute<3><<<2048, 256, 0, stream>>>(
            xT_ws, sorted3, queue3, qc3,
            w3_0, b3_0, w3_1, b3_1, w3_2, b3_2, inds12_ws, out);
    } else {
        reg3_fused<<<HH * 40, 512, 0, stream>>>(
            x_in, w1_0, b1_0, w1_1, b1_1, w1_2, b1_2,
            w2_0, b2_0, w2_1, b2_1, w2_2, b2_2,
            w3_0, b3_0, w3_1, b3_1, w3_2, b3_2, out);
    }
}

// Round 18
// 180.584 us; speedup vs baseline: 1.0291x; 1.0291x over previous
//
#include <hip/hip_runtime.h>

#define HH   112
#define WW   320
#define CIN_ 128
#define HW_  (HH * WW)        // 35840
#define CHUNK 32              // max pixels per queue item (2 rounds of 16)

__device__ __forceinline__ float lrelu(float v) {
    return v >= 0.f ? v : 0.01f * v;
}

// ============================================================================
// K1: stage 1 (per-line grouped 1x1 chain) -> inds1 + xT dump; zeroes qcounts.
// 2 blocks per line (512 thr), 5 tiles of 32 px, 4 chains per wave.
// Layers 2/3 via per-wave ys LDS-broadcast float4; per-output FP accumulation
// order bit-identical to the proven kernel.  [round-12/16 proven, 181us]
// ============================================================================
__global__ __launch_bounds__(512, 2)
void k1_stage1(const float* __restrict__ x_in,
               const float* __restrict__ w1_0, const float* __restrict__ b1_0,
               const float* __restrict__ w1_1, const float* __restrict__ b1_1,
               const float* __restrict__ w1_2, const float* __restrict__ b1_2,
               int* __restrict__ inds1_out, float* __restrict__ xT_out,
               int* __restrict__ qc2, int* __restrict__ qc3)
{
    __shared__ float w1s0[32][CIN_ + 1];
    __shared__ float w1s1[32][33];
    __shared__ float w1s2[16][33];
    __shared__ float b1s[80];
    __shared__ float xT[32][132];          // 32-px tile, float4-aligned rows
    __shared__ float ys[8][4][32];         // [wave][chain][32], wave-private

    const int h   = blockIdx.x >> 1;
    const int q   = blockIdx.x & 1;
    const int tid = threadIdx.x;
    const int base = h * WW;

    if (blockIdx.x == 0 && tid == 0) { *qc2 = 0; *qc3 = 0; }

    for (int n = tid; n < 32 * CIN_; n += 512)
        w1s0[n >> 7][n & 127] = w1_0[h * (32 * CIN_) + n];
    for (int n = tid; n < 32 * 32; n += 512)
        w1s1[n >> 5][n & 31] = w1_1[h * 1024 + n];
    if (tid < 16 * 32)
        w1s2[tid >> 5][tid & 31] = w1_2[h * 512 + tid];
    if      (tid < 32) b1s[tid] = b1_0[h * 32 + tid];
    else if (tid < 64) b1s[tid] = b1_1[h * 32 + (tid - 32)];
    else if (tid < 80) b1s[tid] = b1_2[h * 16 + (tid - 64)];
    __syncthreads();

    const int wave = tid >> 6;
    const int lane = tid & 63;
    const int o    = lane & 31;
    const int half = lane >> 5;
    const int o16  = lane & 15;

    for (int t = 0; t < 5; ++t) {
        const int w0 = q * 160 + t * 32;
        for (int n = tid; n < 32 * CIN_; n += 512) {
            int ww = n & 31, c = n >> 5;
            xT[ww][c] = x_in[c * HW_ + base + w0 + ww];
        }
        __syncthreads();
        for (int n = tid; n < 32 * CIN_; n += 512) {
            int pix = n >> 7, c = n & 127;
            xT_out[(size_t)(base + w0 + pix) * CIN_ + c] = xT[pix][c];
        }

        // ---- layer1 128->32 (weights shared across 4 chains; order exact) ----
        float a0 = 0.f, a1 = 0.f, a2 = 0.f, a3 = 0.f;
        #pragma unroll
        for (int i = 0; i < 64; i += 4) {
            const int ii = half * 64 + i;
            const float w0v = w1s0[o][ii];
            const float w1v = w1s0[o][ii + 1];
            const float w2v = w1s0[o][ii + 2];
            const float w3v = w1s0[o][ii + 3];
            const float4 v0 = *reinterpret_cast<const float4*>(&xT[wave * 4 + 0][ii]);
            const float4 v1 = *reinterpret_cast<const float4*>(&xT[wave * 4 + 1][ii]);
            const float4 v2 = *reinterpret_cast<const float4*>(&xT[wave * 4 + 2][ii]);
            const float4 v3 = *reinterpret_cast<const float4*>(&xT[wave * 4 + 3][ii]);
            a0 += v0.x * w0v; a1 += v1.x * w0v; a2 += v2.x * w0v; a3 += v3.x * w0v;
            a0 += v0.y * w1v; a1 += v1.y * w1v; a2 += v2.y * w1v; a3 += v3.y * w1v;
            a0 += v0.z * w2v; a1 += v1.z * w2v; a2 += v2.z * w2v; a3 += v3.z * w2v;
            a0 += v0.w * w3v; a1 += v1.w * w3v; a2 += v2.w * w3v; a3 += v3.w * w3v;
        }
        a0 += __shfl_xor(a0, 32); a1 += __shfl_xor(a1, 32);
        a2 += __shfl_xor(a2, 32); a3 += __shfl_xor(a3, 32);
        ys[wave][0][o] = lrelu(a0 + b1s[o]);
        ys[wave][1][o] = lrelu(a1 + b1s[o]);
        ys[wave][2][o] = lrelu(a2 + b1s[o]);
        ys[wave][3][o] = lrelu(a3 + b1s[o]);

        // ---- layer2 32->32 via ys broadcast float4 ----
        a0 = a1 = a2 = a3 = 0.f;
        #pragma unroll
        for (int i = 0; i < 32; i += 4) {
            const float w0v = w1s1[o][i];
            const float w1v = w1s1[o][i + 1];
            const float w2v = w1s1[o][i + 2];
            const float w3v = w1s1[o][i + 3];
            const float4 y0 = *reinterpret_cast<const float4*>(&ys[wave][0][i]);
            const float4 y1 = *reinterpret_cast<const float4*>(&ys[wave][1][i]);
            const float4 y2 = *reinterpret_cast<const float4*>(&ys[wave][2][i]);
            const float4 y3 = *reinterpret_cast<const float4*>(&ys[wave][3][i]);
            a0 += y0.x * w0v; a1 += y1.x * w0v; a2 += y2.x * w0v; a3 += y3.x * w0v;
            a0 += y0.y * w1v; a1 += y1.y * w1v; a2 += y2.y * w1v; a3 += y3.y * w1v;
            a0 += y0.z * w2v; a1 += y1.z * w2v; a2 += y2.z * w2v; a3 += y3.z * w2v;
            a0 += y0.w * w3v; a1 += y1.w * w3v; a2 += y2.w * w3v; a3 += y3.w * w3v;
        }
        ys[wave][0][o] = lrelu(a0 + b1s[32 + o]);
        ys[wave][1][o] = lrelu(a1 + b1s[32 + o]);
        ys[wave][2][o] = lrelu(a2 + b1s[32 + o]);
        ys[wave][3][o] = lrelu(a3 + b1s[32 + o]);

        // ---- layer3 32->16 ----
        a0 = a1 = a2 = a3 = 0.f;
        #pragma unroll
        for (int i = 0; i < 32; i += 4) {
            const float w0v = w1s2[o16][i];
            const float w1v = w1s2[o16][i + 1];
            const float w2v = w1s2[o16][i + 2];
            const float w3v = w1s2[o16][i + 3];
            const float4 y0 = *reinterpret_cast<const float4*>(&ys[wave][0][i]);
            const float4 y1 = *reinterpret_cast<const float4*>(&ys[wave][1][i]);
            const float4 y2 = *reinterpret_cast<const float4*>(&ys[wave][2][i]);
            const float4 y3 = *reinterpret_cast<const float4*>(&ys[wave][3][i]);
            a0 += y0.x * w0v; a1 += y1.x * w0v; a2 += y2.x * w0v; a3 += y3.x * w0v;
            a0 += y0.y * w1v; a1 += y1.y * w1v; a2 += y2.y * w1v; a3 += y3.y * w1v;
            a0 += y0.z * w2v; a1 += y1.z * w2v; a2 += y2.z * w2v; a3 += y3.z * w2v;
            a0 += y0.w * w3v; a1 += y1.w * w3v; a2 += y2.w * w3v; a3 += y3.w * w3v;
        }
        float bv0 = a0 + b1s[64 + o16], bv1 = a1 + b1s[64 + o16];
        float bv2 = a2 + b1s[64 + o16], bv3 = a3 + b1s[64 + o16];
        int bi0 = o16, bi1 = o16, bi2 = o16, bi3 = o16;
        #pragma unroll
        for (int d = 1; d < 16; d <<= 1) {
            const float ov0 = __shfl_xor(bv0, d); const int oi0 = __shfl_xor(bi0, d);
            const float ov1 = __shfl_xor(bv1, d); const int oi1 = __shfl_xor(bi1, d);
            const float ov2 = __shfl_xor(bv2, d); const int oi2 = __shfl_xor(bi2, d);
            const float ov3 = __shfl_xor(bv3, d); const int oi3 = __shfl_xor(bi3, d);
            if (ov0 > bv0 || (ov0 == bv0 && oi0 < bi0)) { bv0 = ov0; bi0 = oi0; }
            if (ov1 > bv1 || (ov1 == bv1 && oi1 < bi1)) { bv1 = ov1; bi1 = oi1; }
            if (ov2 > bv2 || (ov2 == bv2 && oi2 < bi2)) { bv2 = ov2; bi2 = oi2; }
            if (ov3 > bv3 || (ov3 == bv3 && oi3 < bi3)) { bv3 = ov3; bi3 = oi3; }
        }
        if (lane == 0) {
            inds1_out[base + w0 + wave * 4 + 0] = bi0;
            inds1_out[base + w0 + wave * 4 + 1] = bi1;
            inds1_out[base + w0 + wave * 4 + 2] = bi2;
            inds1_out[base + w0 + wave * 4 + 3] = bi3;
        }
        __syncthreads();
    }
}

// ============================================================================
// Sorter: one block per line; bucket-sort by (clipped) routing index; emit
// <=CHUNK-pixel work items. Item order nondeterministic, item set + outputs
// deterministic. (round-9/12/16 proven)
// ============================================================================
template <int BINS>
__global__ void sorter(const int* __restrict__ inds_in, int clipmax,
                       int* __restrict__ sorted, int4* __restrict__ queue,
                       int* __restrict__ qcount)
{
    __shared__ int cnt[BINS];
    __shared__ int scan[BINS];
    __shared__ int rank[BINS];

    const int h = blockIdx.x, tid = threadIdx.x, base = h * WW;
    if (tid < BINS) { cnt[tid] = 0; rank[tid] = 0; }
    __syncthreads();

    int c = -1;
    if (tid < WW) {
        c = inds_in[base + tid];
        c = min(max(c, 0), clipmax);
        atomicAdd(&cnt[c], 1);
    }
    __syncthreads();
    if (tid < BINS) scan[tid] = cnt[tid];
    __syncthreads();
    for (int s = 1; s < BINS; s <<= 1) {
        int v = 0;
        if (tid >= s && tid < BINS) v = scan[tid - s];
        __syncthreads();
        if (tid < BINS) scan[tid] += v;
        __syncthreads();
    }
    if (tid < WW) {
        int pos = (scan[c] - cnt[c]) + atomicAdd(&rank[c], 1);
        sorted[base + pos] = base + tid;          // absolute pixel id
    }
    if (tid < BINS && cnt[tid] > 0) {
        int offc = scan[tid] - cnt[tid];
        for (int s0 = 0; s0 < cnt[tid]; s0 += CHUNK) {
            int qi = atomicAdd(qcount, 1);
            queue[qi] = make_int4(h, tid, base + offc + s0,
                                  min(CHUNK, cnt[tid] - s0));
        }
    }
}

// ============================================================================
// Queue-driven CondMul chain — round-9/12/16 proven version (post-timing OK).
// 256 threads (4 waves), block-wide items, weights staged in LDS, 4 chains
// per wave interleaved, named scalars only, bit-exact per-pixel FP order.
// ============================================================================
#define QK_ROUND(TB, PA, PB, PC, PD)                                           \
{                                                                              \
    float a0 = 0.f, a1 = 0.f, a2 = 0.f, a3 = 0.f;                              \
    _Pragma("unroll")                                                          \
    for (int i = 0; i < 64; i += 4) {                                          \
        const int ii = half * 64 + i;                                          \
        const float w0v = ws0[(ii + 0) * 32 + o];                              \
        const float w1v = ws0[(ii + 1) * 32 + o];                              \
        const float w2v = ws0[(ii + 2) * 32 + o];                              \
        const float w3v = ws0[(ii + 3) * 32 + o];                              \
        const float4 v0 = *reinterpret_cast<const float4*>(&xbuf[wave*4+0][ii]);\
        const float4 v1 = *reinterpret_cast<const float4*>(&xbuf[wave*4+1][ii]);\
        const float4 v2 = *reinterpret_cast<const float4*>(&xbuf[wave*4+2][ii]);\
        const float4 v3 = *reinterpret_cast<const float4*>(&xbuf[wave*4+3][ii]);\
        a0 += v0.x * w0v; a1 += v1.x * w0v; a2 += v2.x * w0v; a3 += v3.x * w0v;\
        a0 += v0.y * w1v; a1 += v1.y * w1v; a2 += v2.y * w1v; a3 += v3.y * w1v;\
        a0 += v0.z * w2v; a1 += v1.z * w2v; a2 += v2.z * w2v; a3 += v3.z * w2v;\
        a0 += v0.w * w3v; a1 += v1.w * w3v; a2 += v2.w * w3v; a3 += v3.w * w3v;\
    }                                                                          \
    a0 += __shfl_xor(a0, 32); a1 += __shfl_xor(a1, 32);                        \
    a2 += __shfl_xor(a2, 32); a3 += __shfl_xor(a3, 32);                        \
    ys[wave][0][o] = lrelu(a0 + bs[o]);                                        \
    ys[wave][1][o] = lrelu(a1 + bs[o]);                                        \
    ys[wave][2][o] = lrelu(a2 + bs[o]);                                        \
    ys[wave][3][o] = lrelu(a3 + bs[o]);                                        \
    a0 = a1 = a2 = a3 = 0.f;                                                   \
    _Pragma("unroll")                                                          \
    for (int i = 0; i < 32; i += 4) {                                          \
        const float w0v = ws1[(i + 0) * 32 + o];                               \
        const float w1v = ws1[(i + 1) * 32 + o];                               \
        const float w2v = ws1[(i + 2) * 32 + o];                               \
        const float w3v = ws1[(i + 3) * 32 + o];                               \
        const float4 y0 = *reinterpret_cast<const float4*>(&ys[wave][0][i]);   \
        const float4 y1 = *reinterpret_cast<const float4*>(&ys[wave][1][i]);   \
        const float4 y2 = *reinterpret_cast<const float4*>(&ys[wave][2][i]);   \
        const float4 y3 = *reinterpret_cast<const float4*>(&ys[wave][3][i]);   \
        a0 += y0.x * w0v; a1 += y1.x * w0v; a2 += y2.x * w0v; a3 += y3.x * w0v;\
        a0 += y0.y * w1v; a1 += y1.y * w1v; a2 += y2.y * w1v; a3 += y3.y * w1v;\
        a0 += y0.z * w2v; a1 += y1.z * w2v; a2 += y2.z * w2v; a3 += y3.z * w2v;\
        a0 += y0.w * w3v; a1 += y1.w * w3v; a2 += y2.w * w3v; a3 += y3.w * w3v;\
    }                                                                          \
    ys[wave][0][o] = lrelu(a0 + bs[32 + o]);                                   \
    ys[wave][1][o] = lrelu(a1 + bs[32 + o]);                                   \
    ys[wave][2][o] = lrelu(a2 + bs[32 + o]);                                   \
    ys[wave][3][o] = lrelu(a3 + bs[32 + o]);                                   \
    a0 = a1 = a2 = a3 = 0.f;                                                   \
    _Pragma("unroll")                                                          \
    for (int i = 0; i < 32; i += 4) {                                          \
        const float w0v = ws2[(i + 0) * 32 + o];                               \
        const float w1v = ws2[(i + 1) * 32 + o];                               \
        const float w2v = ws2[(i + 2) * 32 + o];                               \
        const float w3v = ws2[(i + 3) * 32 + o];                               \
        const float4 y0 = *reinterpret_cast<const float4*>(&ys[wave][0][i]);   \
        const float4 y1 = *reinterpret_cast<const float4*>(&ys[wave][1][i]);   \
        const float4 y2 = *reinterpret_cast<const float4*>(&ys[wave][2][i]);   \
        const float4 y3 = *reinterpret_cast<const float4*>(&ys[wave][3][i]);   \
        a0 += y0.x * w0v; a1 += y1.x * w0v; a2 += y2.x * w0v; a3 += y3.x * w0v;\
        a0 += y0.y * w1v; a1 += y1.y * w1v; a2 += y2.y * w1v; a3 += y3.y * w1v;\
        a0 += y0.z * w2v; a1 += y1.z * w2v; a2 += y2.z * w2v; a3 += y3.z * w2v;\
        a0 += y0.w * w3v; a1 += y1.w * w3v; a2 += y2.w * w3v; a3 += y3.w * w3v;\
    }                                                                          \
    float bv0 = a0 + bs[64 + o], bv1 = a1 + bs[64 + o];                        \
    float bv2 = a2 + bs[64 + o], bv3 = a3 + bs[64 + o];                        \
    int bi0 = o, bi1 = o, bi2 = o, bi3 = o;                                    \
    _Pragma("unroll")                                                          \
    for (int d = 1; d < 32; d <<= 1) {                                         \
        const float ov0 = __shfl_xor(bv0, d); const int oi0 = __shfl_xor(bi0, d);\
        const float ov1 = __shfl_xor(bv1, d); const int oi1 = __shfl_xor(bi1, d);\
        const float ov2 = __shfl_xor(bv2, d); const int oi2 = __shfl_xor(bi2, d);\
        const float ov3 = __shfl_xor(bv3, d); const int oi3 = __shfl_xor(bi3, d);\
        if (ov0 > bv0 || (ov0 == bv0 && oi0 < bi0)) { bv0 = ov0; bi0 = oi0; }  \
        if (ov1 > bv1 || (ov1 == bv1 && oi1 < bi1)) { bv1 = ov1; bi1 = oi1; }  \
        if (ov2 > bv2 || (ov2 == bv2 && oi2 < bi2)) { bv2 = ov2; bi2 = oi2; }  \
        if (ov3 > bv3 || (ov3 == bv3 && oi3 < bi3)) { bv3 = ov3; bi3 = oi3; }  \
    }                                                                          \
    if (lane == 0) {                                                           \
        const int tb4 = (TB) + wave * 4;                                       \
        if (STAGE == 2) {                                                      \
            if (tb4 + 0 < n) result[PA] = c * 16 + bi0 - 8;                    \
            if (tb4 + 1 < n) result[PB] = c * 16 + bi1 - 8;                    \
            if (tb4 + 2 < n) result[PC] = c * 16 + bi2 - 8;                    \
            if (tb4 + 3 < n) result[PD] = c * 16 + bi3 - 8;                    \
        } else {                                                               \
            if (tb4 + 0 < n) result[PA] = min(max(inds12_in[PA] * 16 + bi0 - 8, 0), 4095); \
            if (tb4 + 1 < n) result[PB] = min(max(inds12_in[PB] * 16 + bi1 - 8, 0), 4095); \
            if (tb4 + 2 < n) result[PC] = min(max(inds12_in[PC] * 16 + bi2 - 8, 0), 4095); \
            if (tb4 + 3 < n) result[PD] = min(max(inds12_in[PD] * 16 + bi3 - 8, 0), 4095); \
        }                                                                      \
    }                                                                          \
}

template <int STAGE>
__global__ __launch_bounds__(256, 4)
void qk_compute(const float* __restrict__ xT_in, const int* __restrict__ sorted,
                const int4* __restrict__ queue, const int* __restrict__ qcount,
                const float* __restrict__ W0, const float* __restrict__ Bb0,
                const float* __restrict__ W1, const float* __restrict__ Bb1,
                const float* __restrict__ W2, const float* __restrict__ Bb2,
                const int* __restrict__ inds12_in, int* __restrict__ result)
{
    __shared__ float ws0[CIN_ * 32];
    __shared__ float ws1[32 * 32];
    __shared__ float ws2[32 * 32];
    __shared__ float bs[96];
    __shared__ float xbuf[16][CIN_];      // [wave*4+chain][128], per-wave private
    __shared__ float ys[4][4][32];        // [wave][chain][32], per-wave private

    const int tid  = threadIdx.x;
    const int wave = tid >> 6;
    const int lane = tid & 63;
    const int o    = lane & 31;
    const int half = lane >> 5;

    const int qn = *qcount;
    for (int qi = blockIdx.x; qi < qn; qi += gridDim.x) {
        const int4 it4   = queue[qi];
        const int  c     = it4.y;
        const int  start = it4.z;
        const int  n     = it4.w;
        const int  key   = (STAGE == 2) ? (it4.x * 16 + c) : (it4.x * 256 + c);
        const int  nr    = (n + 15) >> 4;
        const int  t0    = wave * 4;

        __syncthreads();                  // all waves done with previous item's LDS

        // ---- prefetch round-0 x (named scalars; 1 float2/pixel/lane) ----
        const int pA0 = sorted[start + min(t0 + 0, n - 1)];
        const int pB0 = sorted[start + min(t0 + 1, n - 1)];
        const int pC0 = sorted[start + min(t0 + 2, n - 1)];
        const int pD0 = sorted[start + min(t0 + 3, n - 1)];
        const float2 xA0 = *reinterpret_cast<const float2*>(&xT_in[(size_t)pA0 * CIN_ + 2 * lane]);
        const float2 xB0 = *reinterpret_cast<const float2*>(&xT_in[(size_t)pB0 * CIN_ + 2 * lane]);
        const float2 xC0 = *reinterpret_cast<const float2*>(&xT_in[(size_t)pC0 * CIN_ + 2 * lane]);
        const float2 xD0 = *reinterpret_cast<const float2*>(&xT_in[(size_t)pD0 * CIN_ + 2 * lane]);

        // ---- stage weight chain into LDS (coalesced float4) ----
        for (int i = tid; i < 1024; i += 256)
            ((float4*)ws0)[i] = ((const float4*)(W0 + (size_t)key * 4096))[i];
        ((float4*)ws1)[tid] = ((const float4*)(W1 + (size_t)key * 1024))[tid];
        ((float4*)ws2)[tid] = ((const float4*)(W2 + (size_t)key * 1024))[tid];
        if      (tid < 32) bs[tid] = Bb0[(size_t)key * 32 + tid];
        else if (tid < 64) bs[tid] = Bb1[(size_t)key * 32 + (tid - 32)];
        else if (tid < 96) bs[tid] = Bb2[(size_t)key * 32 + (tid - 64)];
        __syncthreads();

        // ---- round 0: write prefetched x, prefetch round 1 (scalars) ----
        *reinterpret_cast<float2*>(&xbuf[wave * 4 + 0][2 * lane]) = xA0;
        *reinterpret_cast<float2*>(&xbuf[wave * 4 + 1][2 * lane]) = xB0;
        *reinterpret_cast<float2*>(&xbuf[wave * 4 + 2][2 * lane]) = xC0;
        *reinterpret_cast<float2*>(&xbuf[wave * 4 + 3][2 * lane]) = xD0;

        int pA1 = 0, pB1 = 0, pC1 = 0, pD1 = 0;
        float2 xA1 = {0.f, 0.f}, xB1 = {0.f, 0.f}, xC1 = {0.f, 0.f}, xD1 = {0.f, 0.f};
        if (nr == 2) {
            pA1 = sorted[start + min(16 + t0 + 0, n - 1)];
            pB1 = sorted[start + min(16 + t0 + 1, n - 1)];
            pC1 = sorted[start + min(16 + t0 + 2, n - 1)];
            pD1 = sorted[start + min(16 + t0 + 3, n - 1)];
            xA1 = *reinterpret_cast<const float2*>(&xT_in[(size_t)pA1 * CIN_ + 2 * lane]);
            xB1 = *reinterpret_cast<const float2*>(&xT_in[(size_t)pB1 * CIN_ + 2 * lane]);
            xC1 = *reinterpret_cast<const float2*>(&xT_in[(size_t)pC1 * CIN_ + 2 * lane]);
            xD1 = *reinterpret_cast<const float2*>(&xT_in[(size_t)pD1 * CIN_ + 2 * lane]);
        }

        QK_ROUND(0, pA0, pB0, pC0, pD0)

        if (nr == 2) {
            *reinterpret_cast<float2*>(&xbuf[wave * 4 + 0][2 * lane]) = xA1;
            *reinterpret_cast<float2*>(&xbuf[wave * 4 + 1][2 * lane]) = xB1;
            *reinterpret_cast<float2*>(&xbuf[wave * 4 + 2][2 * lane]) = xC1;
            *reinterpret_cast<float2*>(&xbuf[wave * 4 + 3][2 * lane]) = xD1;
            QK_ROUND(16, pA1, pB1, pC1, pD1)
        }
    }
}

// ============================================================================
// Fallback: proven monolithic kernel (only if d_ws too small — not expected).
// ============================================================================
__global__ __launch_bounds__(512, 4)
void reg3_fused(const float* __restrict__ x_in,
                const float* __restrict__ w1_0, const float* __restrict__ b1_0,
                const float* __restrict__ w1_1, const float* __restrict__ b1_1,
                const float* __restrict__ w1_2, const float* __restrict__ b1_2,
                const float* __restrict__ w2_0, const float* __restrict__ b2_0,
                const float* __restrict__ w2_1, const float* __restrict__ b2_1,
                const float* __restrict__ w2_2, const float* __restrict__ b2_2,
                const float* __restrict__ w3_0, const float* __restrict__ b3_0,
                const float* __restrict__ w3_1, const float* __restrict__ b3_1,
                const float* __restrict__ w3_2, const float* __restrict__ b3_2,
                int* __restrict__ out)
{
    __shared__ float xT[8][CIN_ + 1];
    __shared__ float w1s0[32][CIN_ + 1];
    __shared__ float w1s1[32][33];
    __shared__ float w1s2[16][33];
    __shared__ float b1s[80];

    const int h   = blockIdx.x / 40;
    const int w0  = (blockIdx.x % 40) * 8;
    const int tid = threadIdx.x;

    for (int n = tid; n < 8 * CIN_; n += 512) {
        int ww = n & 7, c = n >> 3;
        xT[ww][c] = x_in[c * HW_ + h * WW + w0 + ww];
    }
    for (int n = tid; n < 32 * CIN_; n += 512)
        w1s0[n >> 7][n & 127] = w1_0[h * (32 * CIN_) + n];
    for (int n = tid; n < 32 * 32; n += 512)
        w1s1[n >> 5][n & 31] = w1_1[h * 1024 + n];
    if (tid < 16 * 32)
        w1s2[tid >> 5][tid & 31] = w1_2[h * 512 + tid];
    if      (tid < 32) b1s[tid] = b1_0[h * 32 + tid];
    else if (tid < 64) b1s[tid] = b1_1[h * 32 + (tid - 32)];
    else if (tid < 80) b1s[tid] = b1_2[h * 16 + (tid - 64)];
    __syncthreads();

    const int wave = tid >> 6, lane = tid & 63;
    const int o = lane & 31, half = lane >> 5, o16 = lane & 15;
    const float* xr = &xT[wave][0];

    float acc = 0.f;
    #pragma unroll
    for (int i = 0; i < 64; ++i) { int ii = half * 64 + i; acc += xr[ii] * w1s0[o][ii]; }
    acc += __shfl_xor(acc, 32);
    float y = lrelu(acc + b1s[o]);
    acc = 0.f;
    #pragma unroll
    for (int i = 0; i < 32; ++i) acc += __shfl(y, i) * w1s1[o][i];
    float y2 = lrelu(acc + b1s[32 + o]);
    acc = 0.f;
    #pragma unroll
    for (int i = 0; i < 32; ++i) acc += __shfl(y2, i) * w1s2[o16][i];
    float t1 = acc + b1s[64 + o16];

    float bv = t1; int bi = o16;
    #pragma unroll
    for (int d = 1; d < 16; d <<= 1) {
        float ov = __shfl_xor(bv, d); int oi = __shfl_xor(bi, d);
        if (ov > bv || (ov == bv && oi < bi)) { bv = ov; bi = oi; }
    }
    const int inds1 = bi;
    const int idx1  = inds1 + 16 * h;

    const float* Wp = w2_0 + (size_t)idx1 * (CIN_ * 32);
    acc = 0.f;
    #pragma unroll
    for (int i = 0; i < 64; ++i) { int ii = half * 64 + i; acc += xr[ii] * Wp[ii * 32 + o]; }
    acc += __shfl_xor(acc, 32);
    y = lrelu(acc + b2_0[idx1 * 32 + o]);
    Wp = w2_1 + (size_t)idx1 * 1024;
    acc = 0.f;
    #pragma unroll
    for (int i = 0; i < 32; ++i) acc += __shfl(y, i) * Wp[i * 32 + o];
    y2 = lrelu(acc + b2_1[idx1 * 32 + o]);
    Wp = w2_2 + (size_t)idx1 * 1024;
    acc = 0.f;
    #pragma unroll
    for (int i = 0; i < 32; ++i) acc += __shfl(y2, i) * Wp[i * 32 + o];
    float y3 = acc + b2_2[idx1 * 32 + o];

    bv = y3; bi = o;
    #pragma unroll
    for (int d = 1; d < 32; d <<= 1) {
        float ov = __shfl_xor(bv, d); int oi = __shfl_xor(bi, d);
        if (ov > bv || (ov == bv && oi < bi)) { bv = ov; bi = oi; }
    }
    const int inds2  = bi;
    const int inds12 = inds1 * 16 + inds2 - 8;
    const int clip12 = min(max(inds12, 0), 255);
    const int idx12  = clip12 + 256 * h;

    Wp = w3_0 + (size_t)idx12 * (CIN_ * 32);
    acc = 0.f;
    #pragma unroll
    for (int i = 0; i < 64; ++i) { int ii = half * 64 + i; acc += xr[ii] * Wp[ii * 32 + o]; }
    acc += __shfl_xor(acc, 32);
    y = lrelu(acc + b3_0[idx12 * 32 + o]);
    Wp = w3_1 + (size_t)idx12 * 1024;
    acc = 0.f;
    #pragma unroll
    for (int i = 0; i < 32; ++i) acc += __shfl(y, i) * Wp[i * 32 + o];
    y2 = lrelu(acc + b3_1[idx12 * 32 + o]);
    Wp = w3_2 + (size_t)idx12 * 1024;
    acc = 0.f;
    #pragma unroll
    for (int i = 0; i < 32; ++i) acc += __shfl(y2, i) * Wp[i * 32 + o];
    y3 = acc + b3_2[idx12 * 32 + o];

    bv = y3; bi = o;
    #pragma unroll
    for (int d = 1; d < 32; d <<= 1) {
        float ov = __shfl_xor(bv, d); int oi = __shfl_xor(bi, d);
        if (ov > bv || (ov == bv && oi < bi)) { bv = ov; bi = oi; }
    }
    int inds123 = inds12 * 16 + bi - 8;
    inds123 = min(max(inds123, 0), 4095);
    if (lane == 0) out[h * WW + w0 + wave] = inds123;
}

extern "C" void kernel_launch(void* const* d_in, const int* in_sizes, int n_in,
                              void* d_out, int out_size, void* d_ws, size_t ws_size,
                              hipStream_t stream)
{
    const float* x_in = (const float*)d_in[0];
    const float* w1_0 = (const float*)d_in[1];
    const float* b1_0 = (const float*)d_in[2];
    const float* w1_1 = (const float*)d_in[3];
    const float* b1_1 = (const float*)d_in[4];
    const float* w1_2 = (const float*)d_in[5];
    const float* b1_2 = (const float*)d_in[6];
    const float* w2_0 = (const float*)d_in[7];
    const float* b2_0 = (const float*)d_in[8];
    const float* w2_1 = (const float*)d_in[9];
    const float* b2_1 = (const float*)d_in[10];
    const float* w2_2 = (const float*)d_in[11];
    const float* b2_2 = (const float*)d_in[12];
    const float* w3_0 = (const float*)d_in[13];
    const float* b3_0 = (const float*)d_in[14];
    const float* w3_1 = (const float*)d_in[15];
    const float* b3_1 = (const float*)d_in[16];
    const float* w3_2 = (const float*)d_in[17];
    const float* b3_2 = (const float*)d_in[18];
    int* out = (int*)d_out;

    // ws layout (bytes)
    char* ws = (char*)d_ws;
    int*   inds1_ws  = (int*)(ws + 0);                 // HW ints
    int*   inds12_ws = (int*)(ws + 143360);            // HW ints
    int*   sorted2   = (int*)(ws + 286720);            // HW ints
    int*   sorted3   = (int*)(ws + 430080);            // HW ints
    int*   qc2       = (int*)(ws + 573440);
    int*   qc3       = (int*)(ws + 573444);
    int4*  queue2    = (int4*)(ws + 573456);           // HW entries max
    int4*  queue3    = (int4*)(ws + 1146896);          // HW entries max
    float* xT_ws     = (float*)(ws + 1720336);         // HW*128 floats
    const size_t NEED = 1720336 + (size_t)HW_ * CIN_ * 4;   // ~20.07 MB

    if (ws_size >= NEED) {
        k1_stage1<<<HH * 2, 512, 0, stream>>>(
            x_in, w1_0, b1_0, w1_1, b1_1, w1_2, b1_2,
            inds1_ws, xT_ws, qc2, qc3);
        sorter<16><<<HH, 512, 0, stream>>>(inds1_ws, 15, sorted2, queue2, qc2);
        qk_compute<2><<<2048, 256, 0, stream>>>(
            xT_ws, sorted2, queue2, qc2,
            w2_0, b2_0, w2_1, b2_1, w2_2, b2_2, nullptr, inds12_ws);
        sorter<256><<<HH, 512, 0, stream>>>(inds12_ws, 255, sorted3, queue3, qc3);
        qk_compute<3><<<2048, 256, 0, stream>>>(
            xT_ws, sorted3, queue3, qc3,
            w3_0, b3_0, w3_1, b3_1, w3_2, b3_2, inds12_ws, out);
    } else {
        reg3_fused<<<HH * 40, 512, 0, stream>>>(
            x_in, w1_0, b1_0, w1_1, b1_1, w1_2, b1_2,
            w2_0, b2_0, w2_1, b2_1, w2_2, b2_2,
            w3_0, b3_0, w3_1, b3_1, w3_2, b3_2, out);
    }
}